// Round 11
// baseline (296.752 us; speedup 1.0000x reference)
//
#include <hip/hip_runtime.h>

#define N_GRAPHS 100000
#define NTYPES 8
#define MAXD 128
#define FEAT 256
#define NB 2          // graph batches of 16 per wave -> 32 graphs/wave
#define GPW (16 * NB)
#define GPB (GPW * 4) // 128 graphs per block
#define ELDA 68       // Ep row stride, floats (272B)

typedef __attribute__((ext_vector_type(8))) short short8;
typedef __attribute__((ext_vector_type(4))) float f32x4;
typedef __attribute__((ext_vector_type(4))) unsigned uint4v;

constexpr int KSN[NTYPES]  = {1, 1, 2, 4, 2, 1, 1, 4};
constexpr int DIMS[NTYPES] = {16, 32, 64, 128, 64, 32, 16, 128};

__device__ __forceinline__ unsigned f2bf_u(float f) {
    unsigned u = __builtin_bit_cast(unsigned, f);
    return (u + 0x7fffu + ((u >> 16) & 1u)) >> 16;   // round-to-nearest-even
}
__device__ __forceinline__ unsigned cvt2(float lo, float hi) {
    return f2bf_u(lo) | (f2bf_u(hi) << 16);
}
__device__ __forceinline__ short8 cvt8(f32x4 a, f32x4 b) {
    uint4v u;
    u.x = cvt2(a.x, a.y); u.y = cvt2(a.z, a.w);
    u.z = cvt2(b.x, b.y); u.w = cvt2(b.z, b.w);
    return __builtin_bit_cast(short8, u);
}

// --- W -> bf16 fragment prepack. wp[(((t*16 + ct)*4 + ks)*4 + cgrp)*16 + c16]
//     = W[t][ct*16 + c16][ks*32 + cgrp*8 .. +7], zero-masked at k >= dim. 512 KB.
__global__ __launch_bounds__(256)
void prepack_w(const float* __restrict__ W, short8* __restrict__ wp)
{
    const int idx  = blockIdx.x * 256 + threadIdx.x;   // 32768
    const int c16  = idx & 15;
    const int cgrp = (idx >> 4) & 3;
    const int ks   = (idx >> 6) & 3;
    const int ct   = (idx >> 8) & 15;
    const int t    = (idx >> 12) & 7;
    const int col  = ct * 16 + c16;
    const int k    = ks * 32 + cgrp * 8;
    const int dim  = 16 << ((0x30123210u >> (4 * t)) & 0xf);
    const float* src = W + ((size_t)t * FEAT + col) * MAXD + k;
    f32x4 a = *(const f32x4*)src;
    f32x4 b = *(const f32x4*)(src + 4);
    #pragma unroll
    for (int j = 0; j < 4; ++j) {
        if (k + j     >= dim) a[j] = 0.f;
        if (k + 4 + j >= dim) b[j] = 0.f;
    }
    wp[idx] = cvt8(a, b);
}

// One type for one wave's 32 graphs. NO barriers, NO x staging: A-fragments
// load directly from x (lane (cgrp,c16) reads 32B of graph g0+b*16+c16 at
// k=ks*32+cgrp*8 -- pairs of dwordx4 fully consume 128B lines). Epilogue
// transposes through wave-private Ep so global stores are dense 1KB bursts.
template<int T, bool PRE>
__device__ __forceinline__ void do_type(const float* __restrict__ x,
                                        const short8* __restrict__ wp,
                                        const float* __restrict__ W,
                                        const float* __restrict__ bias_g,
                                        float* __restrict__ out,
                                        float* __restrict__ ep,
                                        int g0, int lane, int cgrp, int c16)
{
    constexpr int KS = KSN[T];

    // A fragments: graph = b*16 + c16, k = ks*32 + cgrp*8 (+8 more via v1).
    // k may exceed dim for dim-16 types; W is zero-masked there so the
    // garbage-but-in-bounds x values contribute 0.
    short8 a[NB][KS];
    #pragma unroll
    for (int b = 0; b < NB; ++b) {
        const size_t grow = (size_t)(g0 + b * 16 + c16) * NTYPES + T;
        #pragma unroll
        for (int ks = 0; ks < KS; ++ks) {
            const float* rp = x + grow * MAXD + ks * 32 + cgrp * 8;
            f32x4 v0 = __builtin_nontemporal_load((const f32x4*)rp);
            f32x4 v1 = __builtin_nontemporal_load((const f32x4*)rp + 1);
            a[b][ks] = cvt8(v0, v1);
        }
    }

    // 16 feature-tiles; flush Ep as dense 1KB nt stores every 4 tiles
    #pragma unroll
    for (int ct4 = 0; ct4 < 4; ++ct4) {
        #pragma unroll
        for (int c = 0; c < 4; ++c) {
            const int ct = ct4 * 4 + c;
            short8 wf[KS];
            if constexpr (PRE) {
                #pragma unroll
                for (int ks = 0; ks < KS; ++ks)
                    wf[ks] = wp[(((T * 16 + ct) * 4 + ks) * 4 + cgrp) * 16 + c16];
            } else {
                constexpr int DIM = DIMS[T];
                #pragma unroll
                for (int ks = 0; ks < KS; ++ks) {
                    const int k = ks * 32 + cgrp * 8;
                    const float* wfp = W + ((size_t)T * FEAT + ct * 16 + c16) * MAXD + k;
                    f32x4 wa = *(const f32x4*)wfp;
                    f32x4 wb = *(const f32x4*)(wfp + 4);
                    #pragma unroll
                    for (int j = 0; j < 4; ++j) {
                        if (k + j     >= DIM) wa[j] = 0.f;
                        if (k + 4 + j >= DIM) wb[j] = 0.f;
                    }
                    wf[ks] = cvt8(wa, wb);
                }
            }
            #pragma unroll
            for (int b = 0; b < NB; ++b) {
                f32x4 acc = {0.f, 0.f, 0.f, 0.f};
                #pragma unroll
                for (int ks = 0; ks < KS; ++ks)
                    acc = __builtin_amdgcn_mfma_f32_16x16x32_bf16(a[b][ks], wf[ks], acc, 0, 0, 0);
                // D: row (graph) = cgrp*4 + r, col (feat-in-tile) = c16 [m89]
                #pragma unroll
                for (int r = 0; r < 4; ++r)
                    ep[(b * 16 + cgrp * 4 + r) * ELDA + c * 16 + c16] = acc[r];
            }
        }
        // flush: 32 graphs x 64 feats -> 8 instrs x 1KB dense nt stores.
        // In-order DS pipe per wave orders these reads before next ct4's writes.
        #pragma unroll
        for (int i = 0; i < 8; ++i) {
            const int row   = i * 4 + (lane >> 4);    // 0..31
            const int coldw = (lane & 15) * 4;
            f32x4 v  = *(const f32x4*)&ep[row * ELDA + coldw];
            f32x4 b4 = *(const f32x4*)&bias_g[T * FEAT + ct4 * 64 + coldw];
            f32x4 res;
            #pragma unroll
            for (int r = 0; r < 4; ++r) res[r] = v[r] + b4[r];
            __builtin_nontemporal_store(res,
                (f32x4*)&out[(((size_t)(g0 + row)) * NTYPES + T) * FEAT + ct4 * 64 + coldw]);
        }
    }

    if constexpr (T + 1 < NTYPES)
        do_type<T + 1, PRE>(x, wp, W, bias_g, out, ep, g0, lane, cgrp, c16);
}

// 4 fully independent waves per block, 32 graphs each (100000 = 3125*32 ->
// every live wave has a full tile; surplus waves exit whole). Zero
// __syncthreads => no vmcnt(0) pipe drains. LDS = Ep only (34.8 KB/block).
template<bool PRE>
__global__ __launch_bounds__(256, 4)
void node_enc(const float* __restrict__ x, const short8* __restrict__ wp,
              const float* __restrict__ W, const float* __restrict__ bias_g,
              float* __restrict__ out)
{
    __shared__ __align__(16) float Ep[4][GPW * ELDA];  // 4 x 8704 B
    const int tid  = threadIdx.x;
    const int lane = tid & 63;
    const int wave = tid >> 6;
    const int cgrp = lane >> 4;
    const int c16  = lane & 15;
    const int g0   = blockIdx.x * GPB + wave * GPW;
    if (g0 >= N_GRAPHS) return;   // whole-wave exit (last block only)

    do_type<0, PRE>(x, wp, W, bias_g, out, Ep[wave], g0, lane, cgrp, c16);
}

extern "C" void kernel_launch(void* const* d_in, const int* in_sizes, int n_in,
                              void* d_out, int out_size, void* d_ws, size_t ws_size,
                              hipStream_t stream)
{
    const float* x = (const float*)d_in[0];
    const float* W = (const float*)d_in[1];
    const float* b = (const float*)d_in[2];
    float* out = (float*)d_out;

    const int grid = (N_GRAPHS + GPB - 1) / GPB;              // 782
    const size_t wp_bytes = (size_t)32768 * sizeof(short8);   // 512 KB

    if (ws_size >= wp_bytes) {
        short8* wp = (short8*)d_ws;
        prepack_w<<<128, 256, 0, stream>>>(W, wp);
        node_enc<true><<<grid, 256, 0, stream>>>(x, wp, W, b, out);
    } else {
        node_enc<false><<<grid, 256, 0, stream>>>(x, nullptr, W, b, out);
    }
}

// Round 12
// 279.234 us; speedup vs baseline: 1.0627x; 1.0627x over previous
//
#include <hip/hip_runtime.h>

#define N_GRAPHS 100000
#define NTYPES 8
#define MAXD 128
#define FEAT 256
#define ALDA 136   // As row stride, shorts (272B)
#define ELDA 68    // Ep row stride, floats (272B)

typedef __attribute__((ext_vector_type(8))) short short8;
typedef __attribute__((ext_vector_type(4))) float f32x4;
typedef __attribute__((ext_vector_type(4))) unsigned uint4v;

constexpr int KSN[NTYPES]  = {1, 1, 2, 4, 2, 1, 1, 4};
constexpr int DIMS[NTYPES] = {16, 32, 64, 128, 64, 32, 16, 128};

__device__ __forceinline__ unsigned f2bf_u(float f) {
    unsigned u = __builtin_bit_cast(unsigned, f);
    return (u + 0x7fffu + ((u >> 16) & 1u)) >> 16;   // round-to-nearest-even
}
__device__ __forceinline__ unsigned cvt2(float lo, float hi) {
    return f2bf_u(lo) | (f2bf_u(hi) << 16);
}
__device__ __forceinline__ short8 cvt8(f32x4 a, f32x4 b) {
    uint4v u;
    u.x = cvt2(a.x, a.y); u.y = cvt2(a.z, a.w);
    u.z = cvt2(b.x, b.y); u.w = cvt2(b.z, b.w);
    return __builtin_bit_cast(short8, u);
}

// --- W -> bf16 fragment prepack. wp[(((t*16 + ct)*4 + ks)*4 + cgrp)*16 + c16]
//     = W[t][ct*16 + c16][ks*32 + cgrp*8 .. +7], zero-masked at k >= dim. 512 KB.
__global__ __launch_bounds__(256)
void prepack_w(const float* __restrict__ W, short8* __restrict__ wp)
{
    const int idx  = blockIdx.x * 256 + threadIdx.x;   // 32768
    const int c16  = idx & 15;
    const int cgrp = (idx >> 4) & 3;
    const int ks   = (idx >> 6) & 3;
    const int ct   = (idx >> 8) & 15;
    const int t    = (idx >> 12) & 7;
    const int col  = ct * 16 + c16;
    const int k    = ks * 32 + cgrp * 8;
    const int dim  = 16 << ((0x30123210u >> (4 * t)) & 0xf);
    const float* src = W + ((size_t)t * FEAT + col) * MAXD + k;
    f32x4 a = *(const f32x4*)src;
    f32x4 b = *(const f32x4*)(src + 4);
    #pragma unroll
    for (int j = 0; j < 4; ++j) {
        if (k + j     >= dim) a[j] = 0.f;
        if (k + 4 + j >= dim) b[j] = 0.f;
    }
    wp[idx] = cvt8(a, b);
}

// One type for one wave's 16 graphs. No barriers (wave-private As/Ep, in-order
// DS pipe). T14 async-split: type T+1's x loads are ISSUED before compute(T)
// and ds_written to As only after compute(T) -- HBM latency hides under the
// 16-ct MFMA loop. PASSES == KS (16 rows x KS*4 segs / 64 lanes).
template<int T, bool PRE>
__device__ __forceinline__ void do_type(const float* __restrict__ x,
                                        const short8* __restrict__ wp,
                                        const float* __restrict__ W,
                                        const float* __restrict__ bias_g,
                                        float* __restrict__ out,
                                        unsigned short* __restrict__ as_,
                                        float* __restrict__ ep,
                                        int g0, int lane, int cgrp, int c16)
{
    constexpr int KS  = KSN[T];
    constexpr int NXT = (T + 1 < NTYPES) ? T + 1 : T;   // dummy on last type
    constexpr int KSn = KSN[NXT];
    constexpr int SPRn = KSn * 4;                       // 8-float segs per row

    // (1) issue next type's x loads -> regs (vmcnt waited only at step 4)
    f32x4 pv[2 * KSn];
    if constexpr (T + 1 < NTYPES) {
        #pragma unroll
        for (int p = 0; p < KSn; ++p) {
            const int idx = p * 64 + lane;
            const int row = idx / SPRn, s8 = idx % SPRn;
            const float* rp = x + (((size_t)(g0 + row)) * NTYPES + (T + 1)) * MAXD + s8 * 8;
            pv[2 * p]     = __builtin_nontemporal_load((const f32x4*)rp);
            pv[2 * p + 1] = __builtin_nontemporal_load((const f32x4*)rp + 1);
        }
    }

    // (2) A fragments: row = graph = c16, k = ks*32 + cgrp*8; As free after this
    short8 a[KS];
    #pragma unroll
    for (int ks = 0; ks < KS; ++ks)
        a[ks] = *(const short8*)&as_[c16 * ALDA + ks * 32 + cgrp * 8];

    // (3) 16 feature-tiles; flush Ep as dense stores every 4 tiles
    #pragma unroll
    for (int ct4 = 0; ct4 < 4; ++ct4) {
        #pragma unroll
        for (int c = 0; c < 4; ++c) {
            const int ct = ct4 * 4 + c;
            short8 wf[KS];
            if constexpr (PRE) {
                #pragma unroll
                for (int ks = 0; ks < KS; ++ks)
                    wf[ks] = wp[(((T * 16 + ct) * 4 + ks) * 4 + cgrp) * 16 + c16];
            } else {
                constexpr int DIM = DIMS[T];
                #pragma unroll
                for (int ks = 0; ks < KS; ++ks) {
                    const int k = ks * 32 + cgrp * 8;
                    const float* wfp = W + ((size_t)T * FEAT + ct * 16 + c16) * MAXD + k;
                    f32x4 wa = *(const f32x4*)wfp;
                    f32x4 wb = *(const f32x4*)(wfp + 4);
                    #pragma unroll
                    for (int j = 0; j < 4; ++j) {
                        if (k + j     >= DIM) wa[j] = 0.f;
                        if (k + 4 + j >= DIM) wb[j] = 0.f;
                    }
                    wf[ks] = cvt8(wa, wb);
                }
            }
            f32x4 acc = {0.f, 0.f, 0.f, 0.f};
            #pragma unroll
            for (int ks = 0; ks < KS; ++ks)
                acc = __builtin_amdgcn_mfma_f32_16x16x32_bf16(a[ks], wf[ks], acc, 0, 0, 0);
            // D: row (graph) = cgrp*4 + r, col (feat) = ct*16 + c16  [m89]
            #pragma unroll
            for (int r = 0; r < 4; ++r)
                ep[(cgrp * 4 + r) * ELDA + (ct & 3) * 16 + c16] = acc[r];
        }
        // flush: 16 graphs x 64 feats; each instr = 4 rows x 256B full lines
        #pragma unroll
        for (int i = 0; i < 4; ++i) {
            const int row   = i * 4 + (lane >> 4);
            const int coldw = (lane & 15) * 4;
            f32x4 v  = *(const f32x4*)&ep[row * ELDA + coldw];
            f32x4 b4 = *(const f32x4*)&bias_g[T * FEAT + ct4 * 64 + coldw];
            f32x4 res;
            #pragma unroll
            for (int r = 0; r < 4; ++r) res[r] = v[r] + b4[r];
            __builtin_nontemporal_store(res,
                (f32x4*)&out[(((size_t)(g0 + row)) * NTYPES + T) * FEAT + ct4 * 64 + coldw]);
        }
    }

    // (4) vmcnt-wait prefetched x, cvt, ds_write into As (fragments already in regs)
    if constexpr (T + 1 < NTYPES) {
        #pragma unroll
        for (int p = 0; p < KSn; ++p) {
            const int idx = p * 64 + lane;
            const int row = idx / SPRn, s8 = idx % SPRn;
            *(short8*)&as_[row * ALDA + s8 * 8] = cvt8(pv[2 * p], pv[2 * p + 1]);
        }
        do_type<T + 1, PRE>(x, wp, W, bias_g, out, as_, ep, g0, lane, cgrp, c16);
    }
}

// 4 fully independent waves per block, 16 graphs each (100000 = 6250x16; the
// 2 surplus waves of the last block exit whole). Zero __syncthreads.
template<bool PRE>
__global__ __launch_bounds__(256, 3)
void node_enc(const float* __restrict__ x, const short8* __restrict__ wp,
              const float* __restrict__ W, const float* __restrict__ bias_g,
              float* __restrict__ out)
{
    __shared__ __align__(16) unsigned short As[4][16 * ALDA];  // 17408 B
    __shared__ __align__(16) float          Ep[4][16 * ELDA];  // 17408 B
    const int tid  = threadIdx.x;
    const int lane = tid & 63;
    const int wave = tid >> 6;
    const int cgrp = lane >> 4;
    const int c16  = lane & 15;
    const int g0   = blockIdx.x * 64 + wave * 16;
    if (g0 >= N_GRAPHS) return;   // whole-wave exit (last block only)

    unsigned short* as_ = As[wave];
    // prologue: stage T=0 (KS=1 -> one pass)
    {
        const int row = lane >> 2, s8 = lane & 3;
        const float* rp = x + (((size_t)(g0 + row)) * NTYPES + 0) * MAXD + s8 * 8;
        f32x4 v0 = __builtin_nontemporal_load((const f32x4*)rp);
        f32x4 v1 = __builtin_nontemporal_load((const f32x4*)rp + 1);
        *(short8*)&as_[row * ALDA + s8 * 8] = cvt8(v0, v1);
    }

    do_type<0, PRE>(x, wp, W, bias_g, out, as_, Ep[wave], g0, lane, cgrp, c16);
}

extern "C" void kernel_launch(void* const* d_in, const int* in_sizes, int n_in,
                              void* d_out, int out_size, void* d_ws, size_t ws_size,
                              hipStream_t stream)
{
    const float* x = (const float*)d_in[0];
    const float* W = (const float*)d_in[1];
    const float* b = (const float*)d_in[2];
    float* out = (float*)d_out;

    const int grid = (N_GRAPHS + 63) / 64;                    // 1563
    const size_t wp_bytes = (size_t)32768 * sizeof(short8);   // 512 KB

    if (ws_size >= wp_bytes) {
        short8* wp = (short8*)d_ws;
        prepack_w<<<128, 256, 0, stream>>>(W, wp);
        node_enc<true><<<grid, 256, 0, stream>>>(x, wp, W, b, out);
    } else {
        node_enc<false><<<grid, 256, 0, stream>>>(x, nullptr, W, b, out);
    }
}